// Round 1
// baseline (280.071 us; speedup 1.0000x reference)
//
#include <hip/hip_runtime.h>
#include <hip/hip_bf16.h>

// MultiHeadAttention B=4,S=4096,D=64,H=4,HD=16 on gfx950.
// Key identity: softmax over QUERY axis => w[s,t] = E[s,t]/colsum[t],
// attended = E @ (V/colsum).  Two MFMA passes recompute E (cheaper than
// materializing 537MB).  exp(x) = 2^(x*log2e): log2e/4 folded into q.

#define BB 4
#define SS 4096
#define DD 64
#define HH 4
#define HDD 16

typedef unsigned int u32;
typedef unsigned short u16;
typedef __attribute__((ext_vector_type(8))) short bfrag;    // 8 bf16 (4 VGPR)
typedef __attribute__((ext_vector_type(4))) float floatx4;
typedef __attribute__((ext_vector_type(4))) u32 u32x4;

#define LOG2E 1.4426950408889634074f
#define QSCALE (LOG2E * 0.25f)   /* log2(e)/sqrt(HD) */

__device__ __forceinline__ float fexp2(float x) {
#if __has_builtin(__builtin_amdgcn_exp2f)
  return __builtin_amdgcn_exp2f(x);
#else
  return __builtin_exp2f(x);
#endif
}

__device__ __forceinline__ float frcp(float x) {
#if __has_builtin(__builtin_amdgcn_rcpf)
  return __builtin_amdgcn_rcpf(x);
#else
  return 1.0f / x;
#endif
}

// fp32 -> bf16 round-to-nearest-even (values finite; no NaN path needed)
__device__ __forceinline__ u16 f2bf(float f) {
  u32 u = __builtin_bit_cast(u32, f);
  return (u16)((u + 0x7FFFu + ((u >> 16) & 1u)) >> 16);
}

// pack two fp32 -> bf16x2 by truncation (E >= 0; -0.2% bias is harmless here)
__device__ __forceinline__ u32 pack_bf(float lo, float hi) {
  u32 a = __builtin_bit_cast(u32, lo);
  u32 b = __builtin_bit_cast(u32, hi);
  return (a >> 16) | (b & 0xFFFF0000u);
}

// ---------------------------------------------------------------------------
// K1: projections.  x[B,S,64] -> q bf16 (scaled by log2e/4, bias folded),
// k bf16, v fp32; all laid out [B,H,S,16].  32 rows per 256-thread block.
// ---------------------------------------------------------------------------
__global__ __launch_bounds__(256) void k_proj(
    const float* __restrict__ x,
    const float* __restrict__ Wq, const float* __restrict__ bq,
    const float* __restrict__ Wk, const float* __restrict__ bk,
    const float* __restrict__ Wv, const float* __restrict__ bv,
    u16* __restrict__ qb, u16* __restrict__ kb, float* __restrict__ vf)
{
  __shared__ float xs[32 * 64];
  const int tid = threadIdx.x;
  const int blk = blockIdx.x;            // B*S/32 = 512
  const int b   = blk >> 7;
  const int s0  = (blk & 127) << 5;
  const float4* xg = (const float4*)(x + ((size_t)b * SS + s0) * DD);
  float4* xl = (float4*)xs;
  xl[tid]       = xg[tid];
  xl[tid + 256] = xg[tid + 256];
  __syncthreads();

  const int col = tid & 63, h = col >> 4, e = col & 15;
  const int rg  = tid >> 6;              // wave id; 8 rows each
  float aq[8], ak[8], av[8];
#pragma unroll
  for (int r = 0; r < 8; ++r) { aq[r] = 0.f; ak[r] = 0.f; av[r] = 0.f; }
  const int wofs = h * (DD * HDD) + e;
  for (int d = 0; d < DD; ++d) {
    float wq = Wq[wofs + d * HDD];
    float wk = Wk[wofs + d * HDD];
    float wv = Wv[wofs + d * HDD];
    const float* xr = xs + (rg * 8) * 64 + d;   // broadcast within wave
#pragma unroll
    for (int r = 0; r < 8; ++r) {
      float xv = xr[r * 64];
      aq[r] += xv * wq; ak[r] += xv * wk; av[r] += xv * wv;
    }
  }
  const float bqv = bq[col], bkv = bk[col], bvv = bv[col];
  size_t base = ((size_t)(b * HH + h) * SS + (s0 + rg * 8)) * HDD + e;
#pragma unroll
  for (int r = 0; r < 8; ++r) {
    qb[base + r * HDD] = f2bf((aq[r] + bqv) * QSCALE);
    kb[base + r * HDD] = f2bf(ak[r] + bkv);
    vf[base + r * HDD] = av[r] + bvv;
  }
}

// ---------------------------------------------------------------------------
// K2: colsum[t] = sum_s 2^(q[s].k[t]).  MFMA 16x16x32 bf16, K padded 16->32
// (quads 2,3 carry zeros).  A=Q rows (m=lane&15 -> s), B=K rows (n=lane&15
// -> t).  D: row=(lane>>4)*4+reg -> s, col=lane&15 -> t.  Wave owns 32 t.
// ---------------------------------------------------------------------------
__global__ __launch_bounds__(256) void k_colsum(
    const u16* __restrict__ qb, const u16* __restrict__ kb,
    float* __restrict__ csum)
{
  const int tid  = threadIdx.x;
  const int lane = tid & 63, w = tid >> 6;
  const int quad = lane >> 4, l15 = lane & 15;
  const int bh = blockIdx.y;
  const int t0 = blockIdx.x * 128 + w * 32;
  const size_t base = (size_t)bh * (SS * HDD);

  bfrag kf0 = {0,0,0,0,0,0,0,0}, kf1 = {0,0,0,0,0,0,0,0};
  if (quad < 2) {
    kf0 = *(const bfrag*)(kb + base + (size_t)(t0 + l15) * HDD + quad * 8);
    kf1 = *(const bfrag*)(kb + base + (size_t)(t0 + 16 + l15) * HDD + quad * 8);
  }
  const u16* qp = qb + base + (size_t)l15 * HDD + quad * 8;
  const floatx4 z = {0.f, 0.f, 0.f, 0.f};
  float c0 = 0.f, c1 = 0.f;
#pragma unroll 4
  for (int s0 = 0; s0 < SS; s0 += 16) {
    bfrag qf = {0,0,0,0,0,0,0,0};
    if (quad < 2) qf = *(const bfrag*)(qp + s0 * HDD);
    floatx4 d0 = __builtin_amdgcn_mfma_f32_16x16x32_bf16(qf, kf0, z, 0, 0, 0);
    floatx4 d1 = __builtin_amdgcn_mfma_f32_16x16x32_bf16(qf, kf1, z, 0, 0, 0);
    c0 += fexp2(d0[0]) + fexp2(d0[1]) + fexp2(d0[2]) + fexp2(d0[3]);
    c1 += fexp2(d1[0]) + fexp2(d1[1]) + fexp2(d1[2]) + fexp2(d1[3]);
  }
  // reduce the 4 quads (rows s split across quads) for each t = lane&15
  c0 += __shfl_xor(c0, 32, 64); c0 += __shfl_xor(c0, 16, 64);
  c1 += __shfl_xor(c1, 32, 64); c1 += __shfl_xor(c1, 16, 64);
  if (lane < 16) {
    csum[(size_t)bh * SS + t0 + l15]      = c0;
    csum[(size_t)bh * SS + t0 + 16 + l15] = c1;
  }
}

// ---------------------------------------------------------------------------
// K3: v' = v * rcp(colsum[t]), bf16, TRANSPOSED to [B,H,16,S] so the PV
// MFMA B-operand (k=t contiguous per lane) is a 16B global load.
// ---------------------------------------------------------------------------
__global__ __launch_bounds__(256) void k_vprep(
    const float* __restrict__ vf, const float* __restrict__ csum,
    u16* __restrict__ vt)
{
  __shared__ u16 tr[16][264];      // [e][t-local], padded
  __shared__ float rcs[256];
  const int tid = threadIdx.x;
  const int bh  = blockIdx.y;
  const int t0  = blockIdx.x << 8;
  rcs[tid] = frcp(csum[(size_t)bh * SS + t0 + tid]);
  __syncthreads();
  const float* vsrc = vf + ((size_t)bh * SS + t0) * HDD;
#pragma unroll 4
  for (int i = 0; i < 16; ++i) {
    int idx = (i << 8) + tid;
    int tl = idx >> 4, e2 = idx & 15;
    tr[e2][tl] = f2bf(vsrc[idx] * rcs[tl]);
  }
  __syncthreads();
  u16* dst = vt + (size_t)bh * HDD * SS + t0;
#pragma unroll 4
  for (int j = 0; j < 16; ++j)
    dst[(size_t)j * SS + tid] = tr[j][tid];
}

// ---------------------------------------------------------------------------
// K4: attended = E @ v'.  Per wave: one 16-row s-tile, loop t in 32s.
// Scores computed TRANSPOSED (A=K rows -> D'[t][s]) so the LDS write of
// E[s][t] packs reg-pairs into u32s; read back as A-layout via ds_read_b128
// (rows 80B, 16B-aligned).  Per-wave-private tile: intra-wave ordering only.
// ---------------------------------------------------------------------------
__global__ __launch_bounds__(256) void k_attn(
    const u16* __restrict__ qb, const u16* __restrict__ kb,
    const u16* __restrict__ vt, float* __restrict__ att)
{
  __shared__ __align__(16) u32 els[4][16][20];   // [wave][s][32 bf16 + pad]
  const int tid  = threadIdx.x;
  const int lane = tid & 63, w = tid >> 6;
  const int quad = lane >> 4, l15 = lane & 15;
  const int bh = blockIdx.y, b = bh >> 2, h = bh & 3;
  const int s0 = blockIdx.x * 64 + w * 16;
  const size_t base = (size_t)bh * (SS * HDD);

  bfrag qf = {0,0,0,0,0,0,0,0};
  if (quad < 2)
    qf = *(const bfrag*)(qb + base + (size_t)(s0 + l15) * HDD + quad * 8);

  floatx4 acc = {0.f, 0.f, 0.f, 0.f};
  const floatx4 z = {0.f, 0.f, 0.f, 0.f};
  u32* erow = &els[w][l15][0];
  const u16* kp = kb + base + (size_t)l15 * HDD + quad * 8;
  const u16* vp = vt + ((size_t)bh * HDD + l15) * SS + quad * 8;

#pragma unroll 2
  for (int t0 = 0; t0 < SS; t0 += 32) {
    bfrag kf0 = {0,0,0,0,0,0,0,0}, kf1 = {0,0,0,0,0,0,0,0};
    if (quad < 2) {
      kf0 = *(const bfrag*)(kp + t0 * HDD);
      kf1 = *(const bfrag*)(kp + (t0 + 16) * HDD);
    }
    bfrag vfr = *(const bfrag*)(vp + t0);
    // D'[t][s]: row=quad*4+reg -> t-local, col=l15 -> s-local
    floatx4 d0 = __builtin_amdgcn_mfma_f32_16x16x32_bf16(kf0, qf, z, 0, 0, 0);
    floatx4 d1 = __builtin_amdgcn_mfma_f32_16x16x32_bf16(kf1, qf, z, 0, 0, 0);
    // E[s=l15][t]: tile0 -> words quad*2,quad*2+1; tile1 -> +8
    erow[quad * 2 + 0] = pack_bf(fexp2(d0[0]), fexp2(d0[1]));
    erow[quad * 2 + 1] = pack_bf(fexp2(d0[2]), fexp2(d0[3]));
    erow[quad * 2 + 8] = pack_bf(fexp2(d1[0]), fexp2(d1[1]));
    erow[quad * 2 + 9] = pack_bf(fexp2(d1[2]), fexp2(d1[3]));
    // intra-wave DS RAW: DS pipe is in-order per wave; explicit
    // lgkmcnt(0) (vmcnt/expcnt unconstrained; 0xC07F safe on CDNA) to de-risk
    __builtin_amdgcn_s_waitcnt(0xC07F);
    // A-layout: lane reads E[s=l15][t=quad*8..+7] = 16B aligned
    u32x4 et = *(const u32x4*)(erow + quad * 4);
    bfrag ef = __builtin_bit_cast(bfrag, et);
    acc = __builtin_amdgcn_mfma_f32_16x16x32_bf16(ef, vfr, acc, 0, 0, 0);
  }
  // D: row=quad*4+r -> s, col=l15 -> e; write concat layout [B][S][h*16+e]
  float* ao = att + ((size_t)b * SS + s0 + quad * 4) * (HH * HDD) + h * HDD + l15;
#pragma unroll
  for (int r = 0; r < 4; ++r) ao[(size_t)r * (HH * HDD)] = acc[r];
}

// ---------------------------------------------------------------------------
// K5: out_pre = attended_concat @ Wo + bo   (fp32 vector; 134 MFLOP)
// ---------------------------------------------------------------------------
__global__ __launch_bounds__(256) void k_oproj(
    const float* __restrict__ att, const float* __restrict__ Wo,
    const float* __restrict__ bo, float* __restrict__ outp)
{
  const int tid = threadIdx.x;
  const int d = tid & 63, sg = tid >> 6;
  const int blk = blockIdx.x;            // B*S/32 = 512
  const int b = blk >> 7, s0 = (blk & 127) << 5;
  float wo[64];
#pragma unroll
  for (int he = 0; he < 64; ++he) wo[he] = Wo[he * 64 + d];
  const float bov = bo[d];
#pragma unroll 2
  for (int r = 0; r < 8; ++r) {
    int s = s0 + sg * 8 + r;
    const float4* row = (const float4*)(att + ((size_t)b * SS + s) * 64);
    float acc = bov;
#pragma unroll
    for (int j = 0; j < 16; ++j) {
      float4 c = row[j];
      acc += c.x * wo[4*j] + c.y * wo[4*j+1] + c.z * wo[4*j+2] + c.w * wo[4*j+3];
    }
    outp[((size_t)b * SS + s) * 64 + d] = acc;
  }
}

// ---------------------------------------------------------------------------
// K6a: partial column expsums (softmax over s for each (b,d)); deterministic,
// no atomics: part[b][chunk][d].
// ---------------------------------------------------------------------------
__global__ __launch_bounds__(256) void k_esum(
    const float* __restrict__ outp, float* __restrict__ part)
{
  __shared__ float red[4][64];
  const int tid = threadIdx.x, d = tid & 63, sg = tid >> 6;
  const int chunk = blockIdx.x;          // 64 chunks of 64 s
  const int b = blockIdx.y;
  const float* src = outp + ((size_t)b * SS + chunk * 64 + sg * 16) * 64 + d;
  float acc = 0.f;
#pragma unroll 4
  for (int i = 0; i < 16; ++i) acc += fexp2(src[i * 64] * LOG2E);
  red[sg][d] = acc;
  __syncthreads();
  if (tid < 64)
    part[((size_t)b * 64 + chunk) * 64 + tid] =
        red[0][tid] + red[1][tid] + red[2][tid] + red[3][tid];
}

// K6b: out = exp(out_pre) * rcp(colsum_over_s)
__global__ __launch_bounds__(256) void k_softmax(
    const float* __restrict__ outp, const float* __restrict__ part,
    float* __restrict__ out)
{
  __shared__ float rs[64];
  const int tid = threadIdx.x, d = tid & 63, sg = tid >> 6;
  const int st = blockIdx.x;             // 64 s-tiles of 64
  const int b = blockIdx.y;
  if (tid < 64) {
    float e = 0.f;
#pragma unroll 8
    for (int c = 0; c < 64; ++c) e += part[((size_t)b * 64 + c) * 64 + tid];
    rs[tid] = frcp(e);
  }
  __syncthreads();
  const float r = rs[d];
  const size_t rowbase = ((size_t)b * SS + st * 64 + sg * 16) * 64 + d;
#pragma unroll 4
  for (int i = 0; i < 16; ++i)
    out[rowbase + i * 64] = fexp2(outp[rowbase + i * 64] * LOG2E) * r;
}

// ---------------------------------------------------------------------------
extern "C" void kernel_launch(void* const* d_in, const int* in_sizes, int n_in,
                              void* d_out, int out_size, void* d_ws, size_t ws_size,
                              hipStream_t stream) {
  const float* x  = (const float*)d_in[0];
  const float* Wq = (const float*)d_in[1];
  const float* bq = (const float*)d_in[2];
  const float* Wk = (const float*)d_in[3];
  const float* bk = (const float*)d_in[4];
  const float* Wv = (const float*)d_in[5];
  const float* bv = (const float*)d_in[6];
  const float* Wo = (const float*)d_in[7];
  const float* bo = (const float*)d_in[8];

  // workspace layout (42,270,720 B total); aliases are lifetime-disjoint:
  //   att  overlays vf  (vf dead after k_vprep)
  //   outp overlays qb/kb (dead after k_attn)
  char* ws = (char*)d_ws;
  constexpr size_t QB_OFF = 0;                      //  8 MiB u16
  constexpr size_t KB_OFF = (size_t)8  << 20;       //  8 MiB u16
  constexpr size_t VF_OFF = (size_t)16 << 20;       // 16 MiB f32
  constexpr size_t VT_OFF = (size_t)32 << 20;       //  8 MiB u16
  constexpr size_t CS_OFF = (size_t)40 << 20;       // 256 KiB f32
  constexpr size_t PT_OFF = CS_OFF + 262144;        //  64 KiB f32

  u16*   qb   = (u16*)  (ws + QB_OFF);
  u16*   kb   = (u16*)  (ws + KB_OFF);
  float* vf   = (float*)(ws + VF_OFF);
  u16*   vt   = (u16*)  (ws + VT_OFF);
  float* csum = (float*)(ws + CS_OFF);
  float* part = (float*)(ws + PT_OFF);
  float* att  = (float*)(ws + VF_OFF);   // alias vf
  float* outp = (float*)(ws + QB_OFF);   // alias qb+kb
  float* out  = (float*)d_out;

  hipLaunchKernelGGL(k_proj,    dim3(512),     dim3(256), 0, stream,
                     x, Wq, bq, Wk, bk, Wv, bv, qb, kb, vf);
  hipLaunchKernelGGL(k_colsum,  dim3(32, 16),  dim3(256), 0, stream, qb, kb, csum);
  hipLaunchKernelGGL(k_vprep,   dim3(16, 16),  dim3(256), 0, stream, vf, csum, vt);
  hipLaunchKernelGGL(k_attn,    dim3(64, 16),  dim3(256), 0, stream, qb, kb, vt, att);
  hipLaunchKernelGGL(k_oproj,   dim3(512),     dim3(256), 0, stream, att, Wo, bo, outp);
  hipLaunchKernelGGL(k_esum,    dim3(64, 4),   dim3(256), 0, stream, outp, part);
  hipLaunchKernelGGL(k_softmax, dim3(64, 4),   dim3(256), 0, stream, outp, part, out);
}

// Round 2
// 265.382 us; speedup vs baseline: 1.0554x; 1.0554x over previous
//
#include <hip/hip_runtime.h>
#include <hip/hip_bf16.h>

// MultiHeadAttention B=4,S=4096,D=64,H=4,HD=16 on gfx950.
// softmax over QUERY axis => w[s,t] = E[s,t]/colsum[t], attended = E @ (V/colsum).
// Two MFMA passes recompute E.  Scores via 32x32x16 bf16 MFMA (K=16=HD exact).
// exp(x)=2^(x*log2e): log2e/4 folded into q.

#define BB 4
#define SS 4096
#define DD 64
#define HH 4
#define HDD 16

typedef unsigned int u32;
typedef unsigned short u16;
typedef __attribute__((ext_vector_type(8))) short bfrag;     // 8 bf16
typedef __attribute__((ext_vector_type(4))) float floatx4;
typedef __attribute__((ext_vector_type(16))) float floatx16;
typedef __attribute__((ext_vector_type(2))) u32 u32x2;
typedef __attribute__((ext_vector_type(4))) u32 u32x4;

#define LOG2E 1.4426950408889634074f
#define QSCALE (LOG2E * 0.25f)

__device__ __forceinline__ float fexp2(float x) { return __builtin_exp2f(x); }
__device__ __forceinline__ float frcp(float x) { return 1.0f / x; }

__device__ __forceinline__ u16 f2bf(float f) {       // RNE
  u32 u = __builtin_bit_cast(u32, f);
  return (u16)((u + 0x7FFFu + ((u >> 16) & 1u)) >> 16);
}
__device__ __forceinline__ u32 pack_bf(float lo, float hi) {  // truncate (E>=0)
  u32 a = __builtin_bit_cast(u32, lo);
  u32 b = __builtin_bit_cast(u32, hi);
  return (a >> 16) | (b & 0xFFFF0000u);
}

// ---------------------------------------------------------------------------
// K1: projections. x[B,S,64] -> q bf16 (scaled, bias folded), k bf16, v fp32;
// layout [B,H,S,16]. 16 rows per block (grid 1024 for occupancy).
// ---------------------------------------------------------------------------
__global__ __launch_bounds__(256) void k_proj(
    const float* __restrict__ x,
    const float* __restrict__ Wq, const float* __restrict__ bq,
    const float* __restrict__ Wk, const float* __restrict__ bk,
    const float* __restrict__ Wv, const float* __restrict__ bv,
    u16* __restrict__ qb, u16* __restrict__ kb, float* __restrict__ vf)
{
  __shared__ float xs[16 * 64];
  const int tid = threadIdx.x;
  const int blk = blockIdx.x;            // B*S/16 = 1024
  const int b   = blk >> 8;
  const int s0  = (blk & 255) << 4;
  ((float4*)xs)[tid] = ((const float4*)(x + ((size_t)b * SS + s0) * DD))[tid];
  __syncthreads();

  const int col = tid & 63, h = col >> 4, e = col & 15;
  const int rg  = tid >> 6;              // wave id; 4 rows each
  float aq[4] = {0,0,0,0}, ak[4] = {0,0,0,0}, av[4] = {0,0,0,0};
  const int wofs = h * (DD * HDD) + e;
#pragma unroll 4
  for (int d = 0; d < DD; ++d) {
    float wq = Wq[wofs + d * HDD];
    float wk = Wk[wofs + d * HDD];
    float wv = Wv[wofs + d * HDD];
    const float* xr = xs + (rg * 4) * 64 + d;
#pragma unroll
    for (int r = 0; r < 4; ++r) {
      float xv = xr[r * 64];
      aq[r] += xv * wq; ak[r] += xv * wk; av[r] += xv * wv;
    }
  }
  const float bqv = bq[col], bkv = bk[col], bvv = bv[col];
  size_t base = ((size_t)(b * HH + h) * SS + (s0 + rg * 4)) * HDD + e;
#pragma unroll
  for (int r = 0; r < 4; ++r) {
    qb[base + r * HDD] = f2bf((aq[r] + bqv) * QSCALE);
    kb[base + r * HDD] = f2bf(ak[r] + bkv);
    vf[base + r * HDD] = av[r] + bvv;
  }
}

// ---------------------------------------------------------------------------
// K2: partial colsums. Wave owns 32 t (K stationary in A-frag), streams a
// 1024-s chunk of Q through one 32x32x16 MFMA per 32 s. D: col=lane&31 -> s,
// row=(r&3)+8*(r>>2)+4*hl -> t. Cross-lane s-reduce at the end.
// grid (32 t-grp, 4 s-chunk, 16 bh) = 2048 blocks.
// ---------------------------------------------------------------------------
__global__ __launch_bounds__(256) void k_colsum(
    const u16* __restrict__ qb, const u16* __restrict__ kb,
    float* __restrict__ csp)
{
  const int tid = threadIdx.x;
  const int lane = tid & 63, w = tid >> 6;
  const int l31 = lane & 31, hl = lane >> 5;
  const int bh = blockIdx.z, chunk = blockIdx.y;
  const int t0 = blockIdx.x * 128 + w * 32;
  const size_t base = (size_t)bh * (SS * HDD);

  const bfrag kf = *(const bfrag*)(kb + base + (size_t)(t0 + l31) * HDD + hl * 8);
  const u16* qp = qb + base + (size_t)l31 * HDD + hl * 8;
  const floatx16 z16 = {0.f};
  float c[16];
#pragma unroll
  for (int i = 0; i < 16; ++i) c[i] = 0.f;

  const int s0 = chunk * 1024;
#pragma unroll 2
  for (int s = s0; s < s0 + 1024; s += 32) {
    bfrag qfr = *(const bfrag*)(qp + (size_t)s * HDD);
    floatx16 d = __builtin_amdgcn_mfma_f32_32x32x16_bf16(kf, qfr, z16, 0, 0, 0);
#pragma unroll
    for (int i = 0; i < 16; ++i) c[i] += fexp2(d[i]);
  }
#pragma unroll
  for (int i = 0; i < 16; ++i) {
    c[i] += __shfl_xor(c[i], 1,  64);
    c[i] += __shfl_xor(c[i], 2,  64);
    c[i] += __shfl_xor(c[i], 4,  64);
    c[i] += __shfl_xor(c[i], 8,  64);
    c[i] += __shfl_xor(c[i], 16, 64);
  }
  if (l31 == 0) {
    float* dst = csp + ((size_t)bh * 4 + chunk) * SS + t0 + 4 * hl;
#pragma unroll
    for (int r = 0; r < 16; ++r) dst[(r & 3) + 8 * (r >> 2)] = c[r];
  }
}

// ---------------------------------------------------------------------------
// K3: v' = v * rcp(sum of 4 colsum partials), bf16, transposed to [B,H,16,S].
// ---------------------------------------------------------------------------
__global__ __launch_bounds__(256) void k_vprep(
    const float* __restrict__ vf, const float* __restrict__ csp,
    u16* __restrict__ vt)
{
  __shared__ u16 tr[16][264];
  __shared__ float rcs[256];
  const int tid = threadIdx.x;
  const int bh  = blockIdx.y;
  const int t0  = blockIdx.x << 8;
  {
    size_t o = (size_t)bh * 4 * SS + t0 + tid;
    rcs[tid] = frcp(csp[o] + csp[o + SS] + csp[o + 2 * SS] + csp[o + 3 * SS]);
  }
  __syncthreads();
  const float* vsrc = vf + ((size_t)bh * SS + t0) * HDD;
#pragma unroll 4
  for (int i = 0; i < 16; ++i) {
    int idx = (i << 8) + tid;
    int tl = idx >> 4, e2 = idx & 15;
    tr[e2][tl] = f2bf(vsrc[idx] * rcs[tl]);
  }
  __syncthreads();
  u16* dst = vt + (size_t)bh * HDD * SS + t0;
#pragma unroll 4
  for (int j = 0; j < 16; ++j)
    dst[(size_t)j * SS + tid] = tr[j][tid];
}

// ---------------------------------------------------------------------------
// K4: attended partials = E @ v' over a 1024-t quarter.  Wave owns 32 s
// (Q stationary as B-frag).  Per 32 t: 1 score MFMA 32x32x16 -> exp2 ->
// pack -> 4 ds_write_b64 -> 2 ds_read_b128 (A-layout) -> 2 PV MFMA 16x16x32.
// Parity double-buffered per-wave LDS; no explicit waitcnt (in-order DS).
// grid (32 s-tiles, 4 t-split, 16 bh) = 2048 blocks -> 32 waves/CU.
// ---------------------------------------------------------------------------
__global__ __launch_bounds__(256, 6) void k_attn(
    const u16* __restrict__ qb, const u16* __restrict__ kb,
    const u16* __restrict__ vt, float* __restrict__ attp)
{
  __shared__ __align__(16) u32 els[4][2][32][20];  // wave, parity, s-row, 16+4 pad
  const int tid  = threadIdx.x;
  const int lane = tid & 63, w = tid >> 6;
  const int l31 = lane & 31, hl = lane >> 5;
  const int q4 = lane >> 4, l15 = lane & 15;
  const int bh = blockIdx.z, b = bh >> 2, h = bh & 3;
  const int tp = blockIdx.y;
  const int s0 = blockIdx.x * 128 + w * 32;
  const size_t base = (size_t)bh * (SS * HDD);

  const bfrag qf = *(const bfrag*)(qb + base + (size_t)(s0 + l31) * HDD + hl * 8);
  const u16* kp = kb + base + (size_t)l31 * HDD + hl * 8;
  const u16* vp = vt + ((size_t)bh * HDD + l15) * SS + q4 * 8;

  floatx4 acc0 = {0.f, 0.f, 0.f, 0.f}, acc1 = {0.f, 0.f, 0.f, 0.f};
  const floatx16 z16 = {0.f};
  u32* eb0 = &els[w][0][0][0];
  u32* eb1 = &els[w][1][0][0];

  const int tb = tp * 1024;
#define ATTN_BODY(T0, EBUF)                                                    \
  {                                                                            \
    bfrag kf  = *(const bfrag*)(kp + (size_t)(T0) * HDD);                      \
    bfrag vfr = *(const bfrag*)(vp + (T0));                                    \
    floatx16 d = __builtin_amdgcn_mfma_f32_32x32x16_bf16(kf, qf, z16, 0, 0, 0);\
    u32* myrow = (EBUF) + l31 * 20 + 2 * hl;                                   \
    _Pragma("unroll")                                                          \
    for (int g = 0; g < 4; ++g) {                                              \
      u32 w0 = pack_bf(fexp2(d[4 * g + 0]), fexp2(d[4 * g + 1]));              \
      u32 w1 = pack_bf(fexp2(d[4 * g + 2]), fexp2(d[4 * g + 3]));              \
      *(u32x2*)(myrow + 4 * g) = (u32x2){w0, w1};                              \
    }                                                                          \
    u32x4 e0 = *(const u32x4*)((EBUF) + l15 * 20 + 4 * q4);                    \
    u32x4 e1 = *(const u32x4*)((EBUF) + (16 + l15) * 20 + 4 * q4);             \
    acc0 = __builtin_amdgcn_mfma_f32_16x16x32_bf16(                            \
        __builtin_bit_cast(bfrag, e0), vfr, acc0, 0, 0, 0);                    \
    acc1 = __builtin_amdgcn_mfma_f32_16x16x32_bf16(                            \
        __builtin_bit_cast(bfrag, e1), vfr, acc1, 0, 0, 0);                    \
  }

  for (int t0 = tb; t0 < tb + 1024; t0 += 64) {
    ATTN_BODY(t0, eb0)
    ATTN_BODY(t0 + 32, eb1)
  }
#undef ATTN_BODY

  // PV D: col=l15 -> e, row=q4*4+r -> s-local (per 16-s half)
  float* ao = attp + (((size_t)tp * BB + b) * SS + s0 + q4 * 4) * (HH * HDD)
            + h * HDD + l15;
#pragma unroll
  for (int r = 0; r < 4; ++r) {
    ao[(size_t)r * (HH * HDD)]              = acc0[r];
    ao[(size_t)(16 + r) * (HH * HDD)]       = acc1[r];
  }
}

// ---------------------------------------------------------------------------
// K5: out_pre = (sum of 4 attended partials) @ Wo + bo
// ---------------------------------------------------------------------------
__global__ __launch_bounds__(256) void k_oproj(
    const float* __restrict__ att, const float* __restrict__ Wo,
    const float* __restrict__ bo, float* __restrict__ outp)
{
  const int tid = threadIdx.x;
  const int d = tid & 63, sg = tid >> 6;
  const int blk = blockIdx.x;            // 512
  const int b = blk >> 7, s0 = (blk & 127) << 5;
  float wo[64];
#pragma unroll
  for (int he = 0; he < 64; ++he) wo[he] = Wo[he * 64 + d];
  const float bov = bo[d];
  const size_t so = (size_t)BB * SS * 16;   // split stride in floatx4 units
#pragma unroll 2
  for (int r = 0; r < 8; ++r) {
    int s = s0 + sg * 8 + r;
    const floatx4* row = (const floatx4*)(att + ((size_t)b * SS + s) * 64);
    float acc = bov;
#pragma unroll
    for (int j = 0; j < 16; ++j) {
      floatx4 c = row[j] + row[j + so] + row[j + 2 * so] + row[j + 3 * so];
      acc += c[0] * wo[4*j] + c[1] * wo[4*j+1] + c[2] * wo[4*j+2] + c[3] * wo[4*j+3];
    }
    outp[((size_t)b * SS + s) * 64 + d] = acc;
  }
}

// ---------------------------------------------------------------------------
// K6a: partial column expsums for the final softmax over s.
// ---------------------------------------------------------------------------
__global__ __launch_bounds__(256) void k_esum(
    const float* __restrict__ outp, float* __restrict__ part)
{
  __shared__ float red[4][64];
  const int tid = threadIdx.x, d = tid & 63, sg = tid >> 6;
  const int chunk = blockIdx.x;
  const int b = blockIdx.y;
  const float* src = outp + ((size_t)b * SS + chunk * 64 + sg * 16) * 64 + d;
  float acc = 0.f;
#pragma unroll 4
  for (int i = 0; i < 16; ++i) acc += fexp2(src[i * 64] * LOG2E);
  red[sg][d] = acc;
  __syncthreads();
  if (tid < 64)
    part[((size_t)b * 64 + chunk) * 64 + tid] =
        red[0][tid] + red[1][tid] + red[2][tid] + red[3][tid];
}

// K6b: out = exp(out_pre) * rcp(colsum_over_s)
__global__ __launch_bounds__(256) void k_softmax(
    const float* __restrict__ outp, const float* __restrict__ part,
    float* __restrict__ out)
{
  __shared__ float rs[64];
  const int tid = threadIdx.x, d = tid & 63, sg = tid >> 6;
  const int st = blockIdx.x;
  const int b = blockIdx.y;
  if (tid < 64) {
    float e = 0.f;
#pragma unroll 8
    for (int c = 0; c < 64; ++c) e += part[((size_t)b * 64 + c) * 64 + tid];
    rs[tid] = frcp(e);
  }
  __syncthreads();
  const float r = rs[d];
  const size_t rowbase = ((size_t)b * SS + st * 64 + sg * 16) * 64 + d;
#pragma unroll 4
  for (int i = 0; i < 16; ++i)
    out[rowbase + i * 64] = fexp2(outp[rowbase + i * 64] * LOG2E) * r;
}

// ---------------------------------------------------------------------------
extern "C" void kernel_launch(void* const* d_in, const int* in_sizes, int n_in,
                              void* d_out, int out_size, void* d_ws, size_t ws_size,
                              hipStream_t stream) {
  const float* x  = (const float*)d_in[0];
  const float* Wq = (const float*)d_in[1];
  const float* bq = (const float*)d_in[2];
  const float* Wk = (const float*)d_in[3];
  const float* bk = (const float*)d_in[4];
  const float* Wv = (const float*)d_in[5];
  const float* bv = (const float*)d_in[6];
  const float* Wo = (const float*)d_in[7];
  const float* bo = (const float*)d_in[8];

  char* ws = (char*)d_ws;
  constexpr size_t QB_OFF  = 0;                    // 2 MiB u16
  constexpr size_t KB_OFF  = (size_t)2  << 20;     // 2 MiB u16
  constexpr size_t VF_OFF  = (size_t)4  << 20;     // 4 MiB f32
  constexpr size_t VT_OFF  = (size_t)8  << 20;     // 2 MiB u16
  constexpr size_t CSP_OFF = (size_t)10 << 20;     // 1 MiB f32 (4 partials)
  constexpr size_t ATT_OFF = (size_t)11 << 20;     // 16 MiB f32 (4 partials)
  constexpr size_t OUT_OFF = (size_t)27 << 20;     // 4 MiB f32
  constexpr size_t PT_OFF  = (size_t)31 << 20;     // 64 KiB f32

  u16*   qb   = (u16*)  (ws + QB_OFF);
  u16*   kb   = (u16*)  (ws + KB_OFF);
  float* vf   = (float*)(ws + VF_OFF);
  u16*   vt   = (u16*)  (ws + VT_OFF);
  float* csp  = (float*)(ws + CSP_OFF);
  float* attp = (float*)(ws + ATT_OFF);
  float* outp = (float*)(ws + OUT_OFF);
  float* part = (float*)(ws + PT_OFF);
  float* out  = (float*)d_out;

  hipLaunchKernelGGL(k_proj,    dim3(1024),       dim3(256), 0, stream,
                     x, Wq, bq, Wk, bk, Wv, bv, qb, kb, vf);
  hipLaunchKernelGGL(k_colsum,  dim3(32, 4, 16),  dim3(256), 0, stream, qb, kb, csp);
  hipLaunchKernelGGL(k_vprep,   dim3(16, 16),     dim3(256), 0, stream, vf, csp, vt);
  hipLaunchKernelGGL(k_attn,    dim3(32, 4, 16),  dim3(256), 0, stream, qb, kb, vt, attp);
  hipLaunchKernelGGL(k_oproj,   dim3(512),        dim3(256), 0, stream, attp, Wo, bo, outp);
  hipLaunchKernelGGL(k_esum,    dim3(64, 4),      dim3(256), 0, stream, outp, part);
  hipLaunchKernelGGL(k_softmax, dim3(64, 4),      dim3(256), 0, stream, outp, part, out);
}